// Round 11
// baseline (372.917 us; speedup 1.0000x reference)
//
#include <hip/hip_runtime.h>

#define N_NODES 50000
#define MROWS   50048   // N_NODES padded to 128 (391 * 128) - GEMM runs guard-free
#define N_EDGES 800000
#define IN_DIM  128
#define HID     256
#define NGRAPH  256
#define LN_EPS  1e-5f

typedef __attribute__((ext_vector_type(8))) short bf16x8;
typedef __attribute__((ext_vector_type(4))) float f32x4;
typedef __attribute__((ext_vector_type(4))) unsigned int u32x4;

// counting-sort geometry: 128 chunks x 6250 edges; bins split in 2 halves of 25000
#define NCHUNK  128
#define CHUNK   6250
#define HWORDS  12500   // packed u32 words per half (2 bins/word)

// padded CSR capacity (pad each node's edge list to a multiple of 4; max +3/node)
#define PAD_E (N_EDGES + 3 * N_NODES)

// ---------------- workspace layout (32-bit word offsets) ----------------
#define W_DEG      0
#define W_FLAG     (W_DEG + N_NODES)
#define W_BSUM     (W_FLAG + 16)
#define W_BPRE     (W_BSUM + 256)
#define W_GOFF     (W_BPRE + 256)
#define W_OFFS     (W_GOFF + NGRAPH + 8)
#define W_DIS      (W_OFFS + N_NODES + 8)
#define W_CSR      (((W_DIS + N_NODES) + 3) & ~3)
#define W_WT       (W_CSR + 2 * PAD_E)
#define W_ZH       (((W_WT + 81920) + 3) & ~3)
#define W_H        (W_ZH + (MROWS * HID / 2))       // bf16 H (overlaid by sort partials pre-gemm1)

// Wt sub-offsets in ushorts within W_WT (transposed bf16, hi only)
#define WT1 0
#define WT2 32768
#define WT3 98304

__device__ __forceinline__ unsigned short f2b(float f) {
    unsigned int u = __float_as_uint(f);
    unsigned int r = (u + 0x7FFFu + ((u >> 16) & 1u)) >> 16;
    return (unsigned short)r;
}
__device__ __forceinline__ float b2f(unsigned short h) {
    return __uint_as_float(((unsigned int)h) << 16);
}
// 4 bf16 (packed in uint2) -> f32x4  (and/shl pair decode, 4 inst)
__device__ __forceinline__ f32x4 cvt4(uint2 u) {
    f32x4 r;
    r[0] = __uint_as_float(u.x << 16);
    r[1] = __uint_as_float(u.x & 0xffff0000u);
    r[2] = __uint_as_float(u.y << 16);
    r[3] = __uint_as_float(u.y & 0xffff0000u);
    return r;
}

// pass 1: per-(chunk,half) LDS histogram, packed 2x16-bit counts per word.
// Each block self-detects int32 vs int64 (odd u32 words of its chunk are int64 high
// halves -> all zero iff int64); block 0 publishes the flag for later kernels.
__global__ __launch_bounds__(256) void hist_kernel(const void* __restrict__ ei,
                                                   int* __restrict__ flag,
                                                   unsigned int* __restrict__ partial) {
    __shared__ unsigned int h[HWORDS];
    __shared__ int s_is32;
    int c = blockIdx.x >> 1, hf = blockIdx.x & 1;
    int t = threadIdx.x;
    for (int i = t; i < HWORDS; i += 256) h[i] = 0u;
    if (t == 0) s_is32 = 0;
    __syncthreads();
    const unsigned int* eu = (const unsigned int*)ei;
    int e0 = c * CHUNK;
    unsigned int orv = 0;
    for (int k = 0; k < 25; ++k) {
        int e = e0 + t + k * 256;
        if (e < e0 + CHUNK) orv |= eu[2 * e + 1];
    }
    if (orv) s_is32 = 1;   // benign same-value race
    __syncthreads();
    bool is32 = (s_is32 != 0);
    if (blockIdx.x == 0 && t == 0) *flag = s_is32;
    for (int k = 0; k < 25; ++k) {
        int e = e0 + t + k * 256;
        if (e < e0 + CHUNK) {
            int d = is32 ? ((const int*)ei)[N_EDGES + e]
                         : (int)((const long long*)ei)[N_EDGES + e];
            if (((d >= 25000) ? 1 : 0) == hf) {
                int w = (d - hf * 25000) >> 1;
                atomicAdd(&h[w], (d & 1) ? 0x10000u : 1u);
            }
        }
    }
    __syncthreads();
    unsigned int* dst = partial + (size_t)blockIdx.x * HWORDS;
    for (int i = t; i < HWORDS; i += 256) dst[i] = h[i];
}

// pass 2: per bin-pair, exclusive prefix across chunks (in place) + total degree
__global__ __launch_bounds__(256) void merge_kernel(unsigned int* __restrict__ partial,
                                                    int* __restrict__ deg) {
    int w = blockIdx.x * 256 + threadIdx.x;
    if (w >= 25000) return;
    int hf = (w >= HWORDS) ? 1 : 0;
    int wi = w - hf * HWORDS;
    unsigned int run_lo = 0, run_hi = 0;
    for (int c = 0; c < NCHUNK; ++c) {
        size_t idx = ((size_t)(c * 2 + hf)) * HWORDS + wi;
        unsigned int u = partial[idx];
        partial[idx] = run_lo | (run_hi << 16);
        run_lo += u & 0xffffu;
        run_hi += u >> 16;
    }
    deg[2 * w]     = (int)run_lo;
    deg[2 * w + 1] = (int)run_hi;
}

// per-block sums of padded degrees (pad to 4)
__global__ __launch_bounds__(256) void blocksum_kernel(const int* __restrict__ deg,
                                                       int* __restrict__ bsum) {
    int b = blockIdx.x, t = threadIdx.x;
    int i = b * 256 + t;
    int pd = (i < N_NODES) ? ((deg[i] + 3) & ~3) : 0;
    int lane = t & 63, w = t >> 6;
    int s = pd;
    #pragma unroll
    for (int o = 32; o >= 1; o >>= 1) s += __shfl_xor(s, o, 64);
    __shared__ int ws[4];
    if (lane == 0) ws[w] = s;
    __syncthreads();
    if (t == 0) bsum[b] = ws[0] + ws[1] + ws[2] + ws[3];
}

// single tiny block: exclusive scan bsum(196) -> bpre
__global__ __launch_bounds__(256) void scanb_kernel(const int* __restrict__ bsum,
                                                    int* __restrict__ bpre) {
    int t = threadIdx.x;
    int lane = t & 63, w = t >> 6;
    int x = (t < 196) ? bsum[t] : 0;
    int inc = x;
    #pragma unroll
    for (int o = 1; o < 64; o <<= 1) {
        int u = __shfl_up(inc, o, 64);
        if (lane >= o) inc += u;
    }
    __shared__ int wsA[4];
    if (lane == 63) wsA[w] = inc;
    __syncthreads();
    int base = 0;
    for (int k = 0; k < w; ++k) base += wsA[k];
    bpre[t] = base + inc - x;
}

// fused: per-node padded offsets + dis + CSR pad-slot zeroing + graph offsets
__global__ __launch_bounds__(256) void finalize_kernel(const int* __restrict__ deg,
                                                       const int* __restrict__ bpre,
                                                       const void* __restrict__ bt,
                                                       const int* __restrict__ flag,
                                                       int* __restrict__ offs,
                                                       float* __restrict__ dis,
                                                       int2* __restrict__ csr,
                                                       int* __restrict__ goffs) {
    int b = blockIdx.x, t = threadIdx.x;
    int i = b * 256 + t;
    int d = (i < N_NODES) ? deg[i] : 0;
    int pd = (d + 3) & ~3;
    int lane = t & 63, w = t >> 6;
    int inc = pd;
    #pragma unroll
    for (int o = 1; o < 64; o <<= 1) {
        int u = __shfl_up(inc, o, 64);
        if (lane >= o) inc += u;
    }
    __shared__ int ws[4];
    if (lane == 63) ws[w] = inc;
    __syncthreads();
    int base = 0;
    for (int k = 0; k < w; ++k) base += ws[k];
    int pre = base + inc - pd;
    int o = bpre[b] + pre;
    if (i < N_NODES) {
        offs[i] = o;
        dis[i] = rsqrtf((float)d + 1.0f);
        int2 z; z.x = 0; z.y = 0;
        for (int e = o + d; e < o + pd; ++e) csr[e] = z;   // zero pad slots only
        bool is32 = (*flag != 0);
        int bb = is32 ? ((const int*)bt)[i] : (int)((const long long*)bt)[i];
        if (i == 0) {
            for (int g = 0; g <= bb; ++g) goffs[g] = 0;
        } else {
            int pb = is32 ? ((const int*)bt)[i - 1] : (int)((const long long*)bt)[i - 1];
            for (int g = pb + 1; g <= bb; ++g) goffs[g] = i;
        }
        if (i == N_NODES - 1) {
            for (int g = bb + 1; g <= NGRAPH; ++g) goffs[g] = N_NODES;
        }
    }
    if (i == N_NODES - 1) offs[N_NODES] = o + pd;
}

// pass 3: counting-sort scatter (no global atomics); rec.x = src byte-offset (src<<9)
__global__ __launch_bounds__(256) void scatter2_kernel(const void* __restrict__ ei,
                                                       const int* __restrict__ flag,
                                                       const int* __restrict__ offs,
                                                       const float* __restrict__ dis,
                                                       const unsigned int* __restrict__ partial,
                                                       int2* __restrict__ csr) {
    __shared__ unsigned int cur[HWORDS];
    int c = blockIdx.x >> 1, hf = blockIdx.x & 1;
    int t = threadIdx.x;
    for (int i = t; i < HWORDS; i += 256) cur[i] = 0u;
    __syncthreads();
    bool is32 = (*flag != 0);
    const unsigned int* rel = partial + (size_t)blockIdx.x * HWORDS;
    int e0 = c * CHUNK;
    for (int k = 0; k < 25; ++k) {
        int e = e0 + t + k * 256;
        if (e < e0 + CHUNK) {
            int s, d;
            if (is32) {
                const int* p = (const int*)ei;
                s = p[e]; d = p[N_EDGES + e];
            } else {
                const long long* p = (const long long*)ei;
                s = (int)p[e]; d = (int)p[N_EDGES + e];
            }
            if (((d >= 25000) ? 1 : 0) == hf) {
                int w = (d - hf * 25000) >> 1;
                unsigned int old = atomicAdd(&cur[w], (d & 1) ? 0x10000u : 1u);
                unsigned int p0 = (d & 1) ? (old >> 16) : (old & 0xffffu);
                unsigned int rp = rel[w];
                unsigned int r = (d & 1) ? (rp >> 16) : (rp & 0xffffu);
                int pos = offs[d] + (int)r + (int)p0;
                int2 rec;
                rec.x = s << 9;                       // pre-multiplied byte offset into bf16 H
                rec.y = __float_as_int(dis[s] * dis[d]);
                csr[pos] = rec;
            }
        }
    }
}

// x -> bf16 + transpose W1,W2,W3 into [N][K] bf16 (hi only)
#define XSPLIT_BLOCKS 6250
__global__ __launch_bounds__(256) void prep_w(const float* __restrict__ x,
                                              const float* __restrict__ W1,
                                              const float* __restrict__ W2,
                                              const float* __restrict__ W3,
                                              unsigned short* __restrict__ xh,
                                              unsigned short* __restrict__ wt) {
    int b = blockIdx.x;
    int t = threadIdx.x;
    if (b < XSPLIT_BLOCKS) {
        int i = b * 256 + t;
        float4 v = ((const float4*)x)[i];
        ushort4 h;
        h.x = f2b(v.x); h.y = f2b(v.y); h.z = f2b(v.z); h.w = f2b(v.w);
        ((ushort4*)xh)[i] = h;
    } else {
        int wb = b - XSPLIT_BLOCKS;
        const float* W; int K, k, bh;
        if (wb < 128)      { W = W1; K = 128; k = wb;       bh = WT1; }
        else if (wb < 384) { W = W2; K = 256; k = wb - 128; bh = WT2; }
        else               { W = W3; K = 256; k = wb - 384; bh = WT3; }
        int n = t;
        wt[bh + n * K + k] = f2b(W[k * HID + n]);
    }
}

// ---------------- bf16 MFMA GEMM: C = A @ B^T-stored; guard-free; C as bf16 ----------------
__global__ __launch_bounds__(256) void gemm_bf16(const unsigned short* __restrict__ A,
                                                 const unsigned short* __restrict__ B,
                                                 unsigned short* __restrict__ C,
                                                 int K) {
    __shared__ char lds[2 * 128 * 80];   // 20480 B: A, B tiles (128 rows x 64B, 80B pitch)
    int tid = threadIdx.x;
    int bm = blockIdx.x * 128;
    int bn = blockIdx.y * 128;
    int lane = tid & 63, wid = tid >> 6;
    int wm = wid >> 1, wn = wid & 1;
    int lr = lane & 15, lc = lane >> 4;
    f32x4 acc[4][4];
    #pragma unroll
    for (int i = 0; i < 4; ++i)
        #pragma unroll
        for (int j = 0; j < 4; ++j)
            acc[i][j] = (f32x4){0.f, 0.f, 0.f, 0.f};

    for (int k0 = 0; k0 < K; k0 += 32) {
        #pragma unroll
        for (int c8 = 0; c8 < 4; ++c8) {
            const int tile = c8 >> 1;
            const unsigned short* __restrict__ src = (tile == 0) ? A : B;
            int c = ((c8 & 1) << 8) + tid;
            int rr = c >> 2, q = c & 3;
            int row = ((tile == 0) ? bm : bn) + rr;
            u32x4 v = *(const u32x4*)(src + (size_t)row * K + k0 + q * 8);
            *(u32x4*)(lds + tile * 10240 + rr * 80 + q * 16) = v;
        }
        __syncthreads();
        bf16x8 af[4], bf[4];
        #pragma unroll
        for (int f = 0; f < 4; ++f) {
            af[f] = *(const bf16x8*)(lds +         (wm * 64 + f * 16 + lr) * 80 + lc * 16);
            bf[f] = *(const bf16x8*)(lds + 10240 + (wn * 64 + f * 16 + lr) * 80 + lc * 16);
        }
        #pragma unroll
        for (int fi = 0; fi < 4; ++fi) {
            #pragma unroll
            for (int fj = 0; fj < 4; ++fj) {
                acc[fi][fj] = __builtin_amdgcn_mfma_f32_16x16x32_bf16(af[fi], bf[fj], acc[fi][fj], 0, 0, 0);
            }
        }
        __syncthreads();
    }
    #pragma unroll
    for (int fi = 0; fi < 4; ++fi) {
        int rbase = bm + wm * 64 + fi * 16 + lc * 4;
        #pragma unroll
        for (int fj = 0; fj < 4; ++fj) {
            int col = bn + wn * 64 + fj * 16 + lr;
            #pragma unroll
            for (int r = 0; r < 4; ++r) {
                C[(size_t)(rbase + r) * HID + col] = f2b(acc[fi][fj][r]);
            }
        }
    }
}

// ---------------- fused aggregation: 1 node/wave, 4-edge chunks, 4-deep pipeline ----------------
#define DECL_C4(P) int4 P##c0, P##c1; uint2 P##h0, P##h1, P##h2, P##h3;

#define LOAD4(P, idx) do { \
    const int4* _q = (const int4*)(csr + (idx)); \
    P##c0 = _q[0]; P##c1 = _q[1]; \
    P##h0 = *(const uint2*)(Hl + P##c0.x); \
    P##h1 = *(const uint2*)(Hl + P##c0.z); \
    P##h2 = *(const uint2*)(Hl + P##c1.x); \
    P##h3 = *(const uint2*)(Hl + P##c1.z); \
} while (0)

#define FMA4U(hv, wv, a) do { a += cvt4(hv) * (wv); } while (0)

#define CONS4(P, a) do { \
    FMA4U(P##h0, __int_as_float(P##c0.y), a); \
    FMA4U(P##h1, __int_as_float(P##c0.w), a); \
    FMA4U(P##h2, __int_as_float(P##c1.y), a); \
    FMA4U(P##h3, __int_as_float(P##c1.w), a); \
} while (0)

// MODE 0: +bias, ReLU, LayerNorm, write bf16 Z.  MODE 1: +bias, write bf16 rows (for pool).
template <int MODE>
__global__ __launch_bounds__(256) void agg_kernel(const unsigned short* __restrict__ H,
                                                  const float* __restrict__ dis,
                                                  const int* __restrict__ offs,
                                                  const int2* __restrict__ csr,
                                                  const float* __restrict__ bias,
                                                  const float* __restrict__ gamma,
                                                  const float* __restrict__ beta,
                                                  unsigned short* __restrict__ Z) {
    int v = blockIdx.x * 4 + (threadIdx.x >> 6);
    int l = threadIdx.x & 63;
    const char* Hl = (const char*)H + l * 8;   // lane-fixed byte base

    float dv = dis[v];
    uint2 a0u = ((const uint2*)(H + (size_t)v * HID))[l];
    f32x4 acc = cvt4(a0u) * (dv * dv);

    int i = offs[v];
    int n = (offs[v + 1] - i) >> 2;   // padded 4-edge chunk count
    DECL_C4(A)
    DECL_C4(B)
    DECL_C4(C)
    DECL_C4(D)
    if (n > 0) LOAD4(A, i);
    if (n > 1) LOAD4(B, i + 4);
    if (n > 2) LOAD4(C, i + 8);
    if (n > 3) LOAD4(D, i + 12);
    int c = 0;
    // steady state: always 3 chunks in flight behind the one being consumed
    while (c + 8 <= n) {
        CONS4(A, acc); LOAD4(A, i + 16);
        CONS4(B, acc); LOAD4(B, i + 20);
        CONS4(C, acc); LOAD4(C, i + 24);
        CONS4(D, acc); LOAD4(D, i + 28);
        i += 16; c += 4;
    }
    // tail: r in [0..7]; buffers hold chunks c..c+3 (those < n)
    int r = n - c;
    if (r >= 1) { CONS4(A, acc); if (r >= 5) LOAD4(A, i + 16); }
    if (r >= 2) { CONS4(B, acc); if (r >= 6) LOAD4(B, i + 20); }
    if (r >= 3) { CONS4(C, acc); if (r >= 7) LOAD4(C, i + 24); }
    if (r >= 4) CONS4(D, acc);
    if (r >= 5) CONS4(A, acc);
    if (r >= 6) CONS4(B, acc);
    if (r >= 7) CONS4(C, acc);

    f32x4 b4 = *(const f32x4*)(bias + l * 4);
    acc += b4;
    if (MODE == 0) {
        acc[0] = fmaxf(acc[0], 0.f); acc[1] = fmaxf(acc[1], 0.f);
        acc[2] = fmaxf(acc[2], 0.f); acc[3] = fmaxf(acc[3], 0.f);
        float s = acc[0] + acc[1] + acc[2] + acc[3];
        #pragma unroll
        for (int o = 32; o >= 1; o >>= 1) s += __shfl_xor(s, o, 64);
        float mu = s * (1.0f / HID);
        f32x4 d = acc - mu;
        float vs = d[0] * d[0] + d[1] * d[1] + d[2] * d[2] + d[3] * d[3];
        #pragma unroll
        for (int o = 32; o >= 1; o >>= 1) vs += __shfl_xor(vs, o, 64);
        float inv = rsqrtf(vs * (1.0f / HID) + LN_EPS);
        f32x4 g4 = *(const f32x4*)(gamma + l * 4);
        f32x4 be4 = *(const f32x4*)(beta + l * 4);
        ushort4 zh;
        zh.x = f2b(d[0] * inv * g4[0] + be4[0]);
        zh.y = f2b(d[1] * inv * g4[1] + be4[1]);
        zh.z = f2b(d[2] * inv * g4[2] + be4[2]);
        zh.w = f2b(d[3] * inv * g4[3] + be4[3]);
        *(ushort4*)(Z + (size_t)v * HID + l * 4) = zh;
    } else {
        ushort4 zh;
        zh.x = f2b(acc[0]); zh.y = f2b(acc[1]);
        zh.z = f2b(acc[2]); zh.w = f2b(acc[3]);
        *(ushort4*)(Z + (size_t)v * HID + l * 4) = zh;
    }
}

// ---------------- per-graph segment-mean pool over bf16 rows (batch is sorted) ----------------
__global__ __launch_bounds__(256) void pool_kernel(const unsigned short* __restrict__ O,
                                                   const int* __restrict__ goffs,
                                                   float* __restrict__ out) {
    int g = blockIdx.x, t = threadIdx.x;
    int l = t & 63, w = t >> 6;
    int s = goffs[g], e = goffs[g + 1];
    f32x4 acc = (f32x4){0.f, 0.f, 0.f, 0.f};
    for (int v = s + w; v < e; v += 4) {
        uint2 r = ((const uint2*)(O + (size_t)v * HID))[l];
        acc += cvt4(r);
    }
    __shared__ f32x4 red[4][64];
    red[w][l] = acc;
    __syncthreads();
    if (w == 0) {
        f32x4 r0 = red[0][l], r1 = red[1][l], r2 = red[2][l], r3 = red[3][l];
        float inv = 1.0f / (float)(e - s);
        f32x4 o = (r0 + r1 + r2 + r3) * inv;
        *(f32x4*)(out + (size_t)g * HID + l * 4) = o;
    }
}

// ---------------- launch ----------------
extern "C" void kernel_launch(void* const* d_in, const int* in_sizes, int n_in,
                              void* d_out, int out_size, void* d_ws, size_t ws_size,
                              hipStream_t stream) {
    const float* x   = (const float*)d_in[0];
    const float* W1  = (const float*)d_in[1];
    const float* b1  = (const float*)d_in[2];
    const float* g1  = (const float*)d_in[3];
    const float* be1 = (const float*)d_in[4];
    const float* W2  = (const float*)d_in[5];
    const float* b2  = (const float*)d_in[6];
    const float* g2  = (const float*)d_in[7];
    const float* be2 = (const float*)d_in[8];
    const float* W3  = (const float*)d_in[9];
    const float* b3  = (const float*)d_in[10];
    const void*  ei  = d_in[11];
    const void*  bt  = d_in[12];
    float* out = (float*)d_out;

    unsigned int* ws = (unsigned int*)d_ws;
    int*   deg    = (int*)(ws + W_DEG);
    int*   flag   = (int*)(ws + W_FLAG);
    int*   bsum   = (int*)(ws + W_BSUM);
    int*   bpre   = (int*)(ws + W_BPRE);
    int*   goffs  = (int*)(ws + W_GOFF);
    int*   offs   = (int*)(ws + W_OFFS);
    float* dis    = (float*)(ws + W_DIS);
    int2*  csr    = (int2*)(ws + W_CSR);
    unsigned short* wt = (unsigned short*)(ws + W_WT);
    unsigned short* Zbuf = (unsigned short*)(ws + W_ZH);
    unsigned short* xh = Zbuf;          // overlay: x-bf16 dead after gemm1
    unsigned short* Hbuf = (unsigned short*)(ws + W_H);       // bf16 H (MROWS rows)
    unsigned int*   partial = (unsigned int*)(ws + W_H);      // overlay: dead after scatter2

    const int NB = (N_NODES + 255) / 256;  // 196

    hist_kernel<<<2 * NCHUNK, 256, 0, stream>>>(ei, flag, partial);
    merge_kernel<<<(25000 + 255) / 256, 256, 0, stream>>>(partial, deg);
    blocksum_kernel<<<NB, 256, 0, stream>>>(deg, bsum);
    scanb_kernel<<<1, 256, 0, stream>>>(bsum, bpre);
    finalize_kernel<<<NB, 256, 0, stream>>>(deg, bpre, bt, flag, offs, dis, csr, goffs);
    scatter2_kernel<<<2 * NCHUNK, 256, 0, stream>>>(ei, flag, offs, dis, partial, csr);
    prep_w<<<XSPLIT_BLOCKS + 640, 256, 0, stream>>>(x, W1, W2, W3, xh, wt);

    dim3 gg(MROWS / 128, HID / 128);     // (391, 2), guard-free
    const int AB = N_NODES / 4;          // 12500 blocks = 50000 waves = 1 node/wave

    gemm_bf16<<<gg, 256, 0, stream>>>(xh, wt + WT1, Hbuf, IN_DIM);
    agg_kernel<0><<<AB, 256, 0, stream>>>(Hbuf, dis, offs, csr, b1, g1, be1, Zbuf);
    gemm_bf16<<<gg, 256, 0, stream>>>(Zbuf, wt + WT2, Hbuf, HID);
    agg_kernel<0><<<AB, 256, 0, stream>>>(Hbuf, dis, offs, csr, b2, g2, be2, Zbuf);
    gemm_bf16<<<gg, 256, 0, stream>>>(Zbuf, wt + WT3, Hbuf, HID);
    agg_kernel<1><<<AB, 256, 0, stream>>>(Hbuf, dis, offs, csr, b3, nullptr, nullptr, Zbuf);
    pool_kernel<<<NGRAPH, 256, 0, stream>>>(Zbuf, goffs, out);
}

// Round 12
// 362.139 us; speedup vs baseline: 1.0298x; 1.0298x over previous
//
#include <hip/hip_runtime.h>

#define N_NODES 50000
#define MROWS   50048   // N_NODES padded to 128 (391 * 128) - GEMM runs guard-free
#define N_EDGES 800000
#define IN_DIM  128
#define HID     256
#define NGRAPH  256
#define LN_EPS  1e-5f

typedef __attribute__((ext_vector_type(8))) short bf16x8;
typedef __attribute__((ext_vector_type(4))) float f32x4;
typedef __attribute__((ext_vector_type(4))) unsigned int u32x4;

// counting-sort geometry: 128 chunks x 6250 edges; bins split in 2 halves of 25000
#define NCHUNK  128
#define CHUNK   6250
#define HWORDS  12500   // packed u32 words per half (2 bins/word)

// padded CSR capacity (pad each node's edge list to a multiple of 4; max +3/node)
#define PAD_E (N_EDGES + 3 * N_NODES)

// ---------------- workspace layout (32-bit word offsets) ----------------
#define W_DEG      0
#define W_FLAG     (W_DEG + N_NODES)
#define W_BSUM     (W_FLAG + 16)
#define W_BPRE     (W_BSUM + 256)
#define W_GOFF     (W_BPRE + 256)
#define W_OFFS     (W_GOFF + NGRAPH + 8)
#define W_DIS      (W_OFFS + N_NODES + 8)
#define W_CSR      (((W_DIS + N_NODES) + 3) & ~3)
#define W_WT       (W_CSR + 2 * PAD_E)
#define W_ZH       (((W_WT + 81920) + 3) & ~3)
#define W_H        (W_ZH + (MROWS * HID / 2))       // bf16 H (overlaid by sort partials pre-gemm1)

// Wt sub-offsets in ushorts within W_WT (transposed bf16, hi only)
#define WT1 0
#define WT2 32768
#define WT3 98304

__device__ __forceinline__ unsigned short f2b(float f) {
    unsigned int u = __float_as_uint(f);
    unsigned int r = (u + 0x7FFFu + ((u >> 16) & 1u)) >> 16;
    return (unsigned short)r;
}
__device__ __forceinline__ float b2f(unsigned short h) {
    return __uint_as_float(((unsigned int)h) << 16);
}
// 4 bf16 (packed in uint2) -> f32x4  (and/shl pair decode, 4 inst)
__device__ __forceinline__ f32x4 cvt4(uint2 u) {
    f32x4 r;
    r[0] = __uint_as_float(u.x << 16);
    r[1] = __uint_as_float(u.x & 0xffff0000u);
    r[2] = __uint_as_float(u.y << 16);
    r[3] = __uint_as_float(u.y & 0xffff0000u);
    return r;
}

// pass 1: per-(chunk,half) LDS histogram, packed 2x16-bit counts per word.
// Each block self-detects int32 vs int64 (odd u32 words of its chunk are int64 high
// halves -> all zero iff int64); block 0 publishes the flag for later kernels.
__global__ __launch_bounds__(256) void hist_kernel(const void* __restrict__ ei,
                                                   int* __restrict__ flag,
                                                   unsigned int* __restrict__ partial) {
    __shared__ unsigned int h[HWORDS];
    __shared__ int s_is32;
    int c = blockIdx.x >> 1, hf = blockIdx.x & 1;
    int t = threadIdx.x;
    for (int i = t; i < HWORDS; i += 256) h[i] = 0u;
    if (t == 0) s_is32 = 0;
    __syncthreads();
    const unsigned int* eu = (const unsigned int*)ei;
    int e0 = c * CHUNK;
    unsigned int orv = 0;
    for (int k = 0; k < 25; ++k) {
        int e = e0 + t + k * 256;
        if (e < e0 + CHUNK) orv |= eu[2 * e + 1];
    }
    if (orv) s_is32 = 1;   // benign same-value race
    __syncthreads();
    bool is32 = (s_is32 != 0);
    if (blockIdx.x == 0 && t == 0) *flag = s_is32;
    for (int k = 0; k < 25; ++k) {
        int e = e0 + t + k * 256;
        if (e < e0 + CHUNK) {
            int d = is32 ? ((const int*)ei)[N_EDGES + e]
                         : (int)((const long long*)ei)[N_EDGES + e];
            if (((d >= 25000) ? 1 : 0) == hf) {
                int w = (d - hf * 25000) >> 1;
                atomicAdd(&h[w], (d & 1) ? 0x10000u : 1u);
            }
        }
    }
    __syncthreads();
    unsigned int* dst = partial + (size_t)blockIdx.x * HWORDS;
    for (int i = t; i < HWORDS; i += 256) dst[i] = h[i];
}

// pass 2: per bin-pair, exclusive prefix across chunks (in place) + total degree
__global__ __launch_bounds__(256) void merge_kernel(unsigned int* __restrict__ partial,
                                                    int* __restrict__ deg) {
    int w = blockIdx.x * 256 + threadIdx.x;
    if (w >= 25000) return;
    int hf = (w >= HWORDS) ? 1 : 0;
    int wi = w - hf * HWORDS;
    unsigned int run_lo = 0, run_hi = 0;
    for (int c = 0; c < NCHUNK; ++c) {
        size_t idx = ((size_t)(c * 2 + hf)) * HWORDS + wi;
        unsigned int u = partial[idx];
        partial[idx] = run_lo | (run_hi << 16);
        run_lo += u & 0xffffu;
        run_hi += u >> 16;
    }
    deg[2 * w]     = (int)run_lo;
    deg[2 * w + 1] = (int)run_hi;
}

// per-block sums of padded degrees (pad to 4)
__global__ __launch_bounds__(256) void blocksum_kernel(const int* __restrict__ deg,
                                                       int* __restrict__ bsum) {
    int b = blockIdx.x, t = threadIdx.x;
    int i = b * 256 + t;
    int pd = (i < N_NODES) ? ((deg[i] + 3) & ~3) : 0;
    int lane = t & 63, w = t >> 6;
    int s = pd;
    #pragma unroll
    for (int o = 32; o >= 1; o >>= 1) s += __shfl_xor(s, o, 64);
    __shared__ int ws[4];
    if (lane == 0) ws[w] = s;
    __syncthreads();
    if (t == 0) bsum[b] = ws[0] + ws[1] + ws[2] + ws[3];
}

// single tiny block: exclusive scan bsum(196) -> bpre
__global__ __launch_bounds__(256) void scanb_kernel(const int* __restrict__ bsum,
                                                    int* __restrict__ bpre) {
    int t = threadIdx.x;
    int lane = t & 63, w = t >> 6;
    int x = (t < 196) ? bsum[t] : 0;
    int inc = x;
    #pragma unroll
    for (int o = 1; o < 64; o <<= 1) {
        int u = __shfl_up(inc, o, 64);
        if (lane >= o) inc += u;
    }
    __shared__ int wsA[4];
    if (lane == 63) wsA[w] = inc;
    __syncthreads();
    int base = 0;
    for (int k = 0; k < w; ++k) base += wsA[k];
    bpre[t] = base + inc - x;
}

// fused: per-node padded offsets + dis + CSR pad-slot zeroing + graph offsets
__global__ __launch_bounds__(256) void finalize_kernel(const int* __restrict__ deg,
                                                       const int* __restrict__ bpre,
                                                       const void* __restrict__ bt,
                                                       const int* __restrict__ flag,
                                                       int* __restrict__ offs,
                                                       float* __restrict__ dis,
                                                       int2* __restrict__ csr,
                                                       int* __restrict__ goffs) {
    int b = blockIdx.x, t = threadIdx.x;
    int i = b * 256 + t;
    int d = (i < N_NODES) ? deg[i] : 0;
    int pd = (d + 3) & ~3;
    int lane = t & 63, w = t >> 6;
    int inc = pd;
    #pragma unroll
    for (int o = 1; o < 64; o <<= 1) {
        int u = __shfl_up(inc, o, 64);
        if (lane >= o) inc += u;
    }
    __shared__ int ws[4];
    if (lane == 63) ws[w] = inc;
    __syncthreads();
    int base = 0;
    for (int k = 0; k < w; ++k) base += ws[k];
    int pre = base + inc - pd;
    int o = bpre[b] + pre;
    if (i < N_NODES) {
        offs[i] = o;
        dis[i] = rsqrtf((float)d + 1.0f);
        int2 z; z.x = 0; z.y = 0;
        for (int e = o + d; e < o + pd; ++e) csr[e] = z;   // zero pad slots only
        bool is32 = (*flag != 0);
        int bb = is32 ? ((const int*)bt)[i] : (int)((const long long*)bt)[i];
        if (i == 0) {
            for (int g = 0; g <= bb; ++g) goffs[g] = 0;
        } else {
            int pb = is32 ? ((const int*)bt)[i - 1] : (int)((const long long*)bt)[i - 1];
            for (int g = pb + 1; g <= bb; ++g) goffs[g] = i;
        }
        if (i == N_NODES - 1) {
            for (int g = bb + 1; g <= NGRAPH; ++g) goffs[g] = N_NODES;
        }
    }
    if (i == N_NODES - 1) offs[N_NODES] = o + pd;
}

// pass 3: counting-sort scatter (no global atomics); rec.x = src byte-offset (src<<9)
__global__ __launch_bounds__(256) void scatter2_kernel(const void* __restrict__ ei,
                                                       const int* __restrict__ flag,
                                                       const int* __restrict__ offs,
                                                       const float* __restrict__ dis,
                                                       const unsigned int* __restrict__ partial,
                                                       int2* __restrict__ csr) {
    __shared__ unsigned int cur[HWORDS];
    int c = blockIdx.x >> 1, hf = blockIdx.x & 1;
    int t = threadIdx.x;
    for (int i = t; i < HWORDS; i += 256) cur[i] = 0u;
    __syncthreads();
    bool is32 = (*flag != 0);
    const unsigned int* rel = partial + (size_t)blockIdx.x * HWORDS;
    int e0 = c * CHUNK;
    for (int k = 0; k < 25; ++k) {
        int e = e0 + t + k * 256;
        if (e < e0 + CHUNK) {
            int s, d;
            if (is32) {
                const int* p = (const int*)ei;
                s = p[e]; d = p[N_EDGES + e];
            } else {
                const long long* p = (const long long*)ei;
                s = (int)p[e]; d = (int)p[N_EDGES + e];
            }
            if (((d >= 25000) ? 1 : 0) == hf) {
                int w = (d - hf * 25000) >> 1;
                unsigned int old = atomicAdd(&cur[w], (d & 1) ? 0x10000u : 1u);
                unsigned int p0 = (d & 1) ? (old >> 16) : (old & 0xffffu);
                unsigned int rp = rel[w];
                unsigned int r = (d & 1) ? (rp >> 16) : (rp & 0xffffu);
                int pos = offs[d] + (int)r + (int)p0;
                int2 rec;
                rec.x = s << 9;                       // pre-multiplied byte offset into bf16 H
                rec.y = __float_as_int(dis[s] * dis[d]);
                csr[pos] = rec;
            }
        }
    }
}

// x -> bf16 + transpose W1,W2,W3 into [N][K] bf16 (hi only)
#define XSPLIT_BLOCKS 6250
__global__ __launch_bounds__(256) void prep_w(const float* __restrict__ x,
                                              const float* __restrict__ W1,
                                              const float* __restrict__ W2,
                                              const float* __restrict__ W3,
                                              unsigned short* __restrict__ xh,
                                              unsigned short* __restrict__ wt) {
    int b = blockIdx.x;
    int t = threadIdx.x;
    if (b < XSPLIT_BLOCKS) {
        int i = b * 256 + t;
        float4 v = ((const float4*)x)[i];
        ushort4 h;
        h.x = f2b(v.x); h.y = f2b(v.y); h.z = f2b(v.z); h.w = f2b(v.w);
        ((ushort4*)xh)[i] = h;
    } else {
        int wb = b - XSPLIT_BLOCKS;
        const float* W; int K, k, bh;
        if (wb < 128)      { W = W1; K = 128; k = wb;       bh = WT1; }
        else if (wb < 384) { W = W2; K = 256; k = wb - 128; bh = WT2; }
        else               { W = W3; K = 256; k = wb - 384; bh = WT3; }
        int n = t;
        wt[bh + n * K + k] = f2b(W[k * HID + n]);
    }
}

// ---------------- bf16 MFMA GEMM: C = A @ B^T-stored; guard-free; C as bf16 ----------------
__global__ __launch_bounds__(256) void gemm_bf16(const unsigned short* __restrict__ A,
                                                 const unsigned short* __restrict__ B,
                                                 unsigned short* __restrict__ C,
                                                 int K) {
    __shared__ char lds[2 * 128 * 80];   // 20480 B: A, B tiles (128 rows x 64B, 80B pitch)
    int tid = threadIdx.x;
    int bm = blockIdx.x * 128;
    int bn = blockIdx.y * 128;
    int lane = tid & 63, wid = tid >> 6;
    int wm = wid >> 1, wn = wid & 1;
    int lr = lane & 15, lc = lane >> 4;
    f32x4 acc[4][4];
    #pragma unroll
    for (int i = 0; i < 4; ++i)
        #pragma unroll
        for (int j = 0; j < 4; ++j)
            acc[i][j] = (f32x4){0.f, 0.f, 0.f, 0.f};

    for (int k0 = 0; k0 < K; k0 += 32) {
        #pragma unroll
        for (int c8 = 0; c8 < 4; ++c8) {
            const int tile = c8 >> 1;
            const unsigned short* __restrict__ src = (tile == 0) ? A : B;
            int c = ((c8 & 1) << 8) + tid;
            int rr = c >> 2, q = c & 3;
            int row = ((tile == 0) ? bm : bn) + rr;
            u32x4 v = *(const u32x4*)(src + (size_t)row * K + k0 + q * 8);
            *(u32x4*)(lds + tile * 10240 + rr * 80 + q * 16) = v;
        }
        __syncthreads();
        bf16x8 af[4], bf[4];
        #pragma unroll
        for (int f = 0; f < 4; ++f) {
            af[f] = *(const bf16x8*)(lds +         (wm * 64 + f * 16 + lr) * 80 + lc * 16);
            bf[f] = *(const bf16x8*)(lds + 10240 + (wn * 64 + f * 16 + lr) * 80 + lc * 16);
        }
        #pragma unroll
        for (int fi = 0; fi < 4; ++fi) {
            #pragma unroll
            for (int fj = 0; fj < 4; ++fj) {
                acc[fi][fj] = __builtin_amdgcn_mfma_f32_16x16x32_bf16(af[fi], bf[fj], acc[fi][fj], 0, 0, 0);
            }
        }
        __syncthreads();
    }
    #pragma unroll
    for (int fi = 0; fi < 4; ++fi) {
        int rbase = bm + wm * 64 + fi * 16 + lc * 4;
        #pragma unroll
        for (int fj = 0; fj < 4; ++fj) {
            int col = bn + wn * 64 + fj * 16 + lr;
            #pragma unroll
            for (int r = 0; r < 4; ++r) {
                C[(size_t)(rbase + r) * HID + col] = f2b(acc[fi][fj][r]);
            }
        }
    }
}

// ---------------- fused aggregation: 1 node/wave, 4-edge chunks, 3-deep pipeline ----------------
#define DECL_C4(P) int4 P##c0, P##c1; uint2 P##h0, P##h1, P##h2, P##h3;

#define LOAD4(P, idx) do { \
    const int4* _q = (const int4*)(csr + (idx)); \
    P##c0 = _q[0]; P##c1 = _q[1]; \
    P##h0 = *(const uint2*)(Hl + P##c0.x); \
    P##h1 = *(const uint2*)(Hl + P##c0.z); \
    P##h2 = *(const uint2*)(Hl + P##c1.x); \
    P##h3 = *(const uint2*)(Hl + P##c1.z); \
} while (0)

#define FMA4U(hv, wv, a) do { a += cvt4(hv) * (wv); } while (0)

#define CONS4(P, a) do { \
    FMA4U(P##h0, __int_as_float(P##c0.y), a); \
    FMA4U(P##h1, __int_as_float(P##c0.w), a); \
    FMA4U(P##h2, __int_as_float(P##c1.y), a); \
    FMA4U(P##h3, __int_as_float(P##c1.w), a); \
} while (0)

// MODE 0: +bias, ReLU, LayerNorm, write bf16 Z.  MODE 1: +bias, write bf16 rows (for pool).
template <int MODE>
__global__ __launch_bounds__(256) void agg_kernel(const unsigned short* __restrict__ H,
                                                  const float* __restrict__ dis,
                                                  const int* __restrict__ offs,
                                                  const int2* __restrict__ csr,
                                                  const float* __restrict__ bias,
                                                  const float* __restrict__ gamma,
                                                  const float* __restrict__ beta,
                                                  unsigned short* __restrict__ Z) {
    int v = blockIdx.x * 4 + (threadIdx.x >> 6);
    int l = threadIdx.x & 63;
    const char* Hl = (const char*)H + l * 8;   // lane-fixed byte base

    float dv = dis[v];
    uint2 a0u = ((const uint2*)(H + (size_t)v * HID))[l];
    f32x4 acc = cvt4(a0u) * (dv * dv);

    int i = offs[v];
    int n = (offs[v + 1] - i) >> 2;   // padded 4-edge chunk count
    DECL_C4(A)
    DECL_C4(B)
    DECL_C4(C)
    if (n > 0) LOAD4(A, i);
    if (n > 1) LOAD4(B, i + 4);
    if (n > 2) LOAD4(C, i + 8);
    int c = 0;
    // steady state: always 2 chunks in flight behind the one being consumed
    while (c + 6 <= n) {
        CONS4(A, acc); LOAD4(A, i + 12);
        CONS4(B, acc); LOAD4(B, i + 16);
        CONS4(C, acc); LOAD4(C, i + 20);
        i += 12; c += 3;
    }
    // tail: r in [0..5]; buffers hold chunks c, c+1, c+2 (those < n)
    int r = n - c;
    if (r >= 1) { CONS4(A, acc); if (r >= 4) LOAD4(A, i + 12); }
    if (r >= 2) { CONS4(B, acc); if (r >= 5) LOAD4(B, i + 16); }
    if (r >= 3) CONS4(C, acc);
    if (r >= 4) CONS4(A, acc);
    if (r >= 5) CONS4(B, acc);

    f32x4 b4 = *(const f32x4*)(bias + l * 4);
    acc += b4;
    if (MODE == 0) {
        acc[0] = fmaxf(acc[0], 0.f); acc[1] = fmaxf(acc[1], 0.f);
        acc[2] = fmaxf(acc[2], 0.f); acc[3] = fmaxf(acc[3], 0.f);
        float s = acc[0] + acc[1] + acc[2] + acc[3];
        #pragma unroll
        for (int o = 32; o >= 1; o >>= 1) s += __shfl_xor(s, o, 64);
        float mu = s * (1.0f / HID);
        f32x4 d = acc - mu;
        float vs = d[0] * d[0] + d[1] * d[1] + d[2] * d[2] + d[3] * d[3];
        #pragma unroll
        for (int o = 32; o >= 1; o >>= 1) vs += __shfl_xor(vs, o, 64);
        float inv = rsqrtf(vs * (1.0f / HID) + LN_EPS);
        f32x4 g4 = *(const f32x4*)(gamma + l * 4);
        f32x4 be4 = *(const f32x4*)(beta + l * 4);
        ushort4 zh;
        zh.x = f2b(d[0] * inv * g4[0] + be4[0]);
        zh.y = f2b(d[1] * inv * g4[1] + be4[1]);
        zh.z = f2b(d[2] * inv * g4[2] + be4[2]);
        zh.w = f2b(d[3] * inv * g4[3] + be4[3]);
        *(ushort4*)(Z + (size_t)v * HID + l * 4) = zh;
    } else {
        ushort4 zh;
        zh.x = f2b(acc[0]); zh.y = f2b(acc[1]);
        zh.z = f2b(acc[2]); zh.w = f2b(acc[3]);
        *(ushort4*)(Z + (size_t)v * HID + l * 4) = zh;
    }
}

// ---------------- per-graph segment-mean pool over bf16 rows (batch is sorted) ----------------
__global__ __launch_bounds__(256) void pool_kernel(const unsigned short* __restrict__ O,
                                                   const int* __restrict__ goffs,
                                                   float* __restrict__ out) {
    int g = blockIdx.x, t = threadIdx.x;
    int l = t & 63, w = t >> 6;
    int s = goffs[g], e = goffs[g + 1];
    f32x4 acc = (f32x4){0.f, 0.f, 0.f, 0.f};
    for (int v = s + w; v < e; v += 4) {
        uint2 r = ((const uint2*)(O + (size_t)v * HID))[l];
        acc += cvt4(r);
    }
    __shared__ f32x4 red[4][64];
    red[w][l] = acc;
    __syncthreads();
    if (w == 0) {
        f32x4 r0 = red[0][l], r1 = red[1][l], r2 = red[2][l], r3 = red[3][l];
        float inv = 1.0f / (float)(e - s);
        f32x4 o = (r0 + r1 + r2 + r3) * inv;
        *(f32x4*)(out + (size_t)g * HID + l * 4) = o;
    }
}

// ---------------- launch ----------------
extern "C" void kernel_launch(void* const* d_in, const int* in_sizes, int n_in,
                              void* d_out, int out_size, void* d_ws, size_t ws_size,
                              hipStream_t stream) {
    const float* x   = (const float*)d_in[0];
    const float* W1  = (const float*)d_in[1];
    const float* b1  = (const float*)d_in[2];
    const float* g1  = (const float*)d_in[3];
    const float* be1 = (const float*)d_in[4];
    const float* W2  = (const float*)d_in[5];
    const float* b2  = (const float*)d_in[6];
    const float* g2  = (const float*)d_in[7];
    const float* be2 = (const float*)d_in[8];
    const float* W3  = (const float*)d_in[9];
    const float* b3  = (const float*)d_in[10];
    const void*  ei  = d_in[11];
    const void*  bt  = d_in[12];
    float* out = (float*)d_out;

    unsigned int* ws = (unsigned int*)d_ws;
    int*   deg    = (int*)(ws + W_DEG);
    int*   flag   = (int*)(ws + W_FLAG);
    int*   bsum   = (int*)(ws + W_BSUM);
    int*   bpre   = (int*)(ws + W_BPRE);
    int*   goffs  = (int*)(ws + W_GOFF);
    int*   offs   = (int*)(ws + W_OFFS);
    float* dis    = (float*)(ws + W_DIS);
    int2*  csr    = (int2*)(ws + W_CSR);
    unsigned short* wt = (unsigned short*)(ws + W_WT);
    unsigned short* Zbuf = (unsigned short*)(ws + W_ZH);
    unsigned short* xh = Zbuf;          // overlay: x-bf16 dead after gemm1
    unsigned short* Hbuf = (unsigned short*)(ws + W_H);       // bf16 H (MROWS rows)
    unsigned int*   partial = (unsigned int*)(ws + W_H);      // overlay: dead after scatter2

    const int NB = (N_NODES + 255) / 256;  // 196

    hist_kernel<<<2 * NCHUNK, 256, 0, stream>>>(ei, flag, partial);
    merge_kernel<<<(25000 + 255) / 256, 256, 0, stream>>>(partial, deg);
    blocksum_kernel<<<NB, 256, 0, stream>>>(deg, bsum);
    scanb_kernel<<<1, 256, 0, stream>>>(bsum, bpre);
    finalize_kernel<<<NB, 256, 0, stream>>>(deg, bpre, bt, flag, offs, dis, csr, goffs);
    scatter2_kernel<<<2 * NCHUNK, 256, 0, stream>>>(ei, flag, offs, dis, partial, csr);
    prep_w<<<XSPLIT_BLOCKS + 640, 256, 0, stream>>>(x, W1, W2, W3, xh, wt);

    dim3 gg(MROWS / 128, HID / 128);     // (391, 2), guard-free
    const int AB = N_NODES / 4;          // 12500 blocks = 50000 waves = 1 node/wave

    gemm_bf16<<<gg, 256, 0, stream>>>(xh, wt + WT1, Hbuf, IN_DIM);
    agg_kernel<0><<<AB, 256, 0, stream>>>(Hbuf, dis, offs, csr, b1, g1, be1, Zbuf);
    gemm_bf16<<<gg, 256, 0, stream>>>(Zbuf, wt + WT2, Hbuf, HID);
    agg_kernel<0><<<AB, 256, 0, stream>>>(Hbuf, dis, offs, csr, b2, g2, be2, Zbuf);
    gemm_bf16<<<gg, 256, 0, stream>>>(Zbuf, wt + WT3, Hbuf, HID);
    agg_kernel<1><<<AB, 256, 0, stream>>>(Hbuf, dis, offs, csr, b3, nullptr, nullptr, Zbuf);
    pool_kernel<<<NGRAPH, 256, 0, stream>>>(Zbuf, goffs, out);
}